// Round 21
// baseline (221.805 us; speedup 1.0000x reference)
//
#include <hip/hip_runtime.h>
#include <hip/hip_fp16.h>

#define MARGIN 6e-4f
#define RCAP 48

typedef __attribute__((ext_vector_type(8))) _Float16 half8;
typedef __attribute__((ext_vector_type(4))) float f32x4;

// RNE f32 -> fp16 bits (validated r12-r20)
__device__ __forceinline__ unsigned short f2h(float x) {
    __half h = __float2half(x);
    return *reinterpret_cast<unsigned short*>(&h);
}
__device__ __forceinline__ void gload16(const void* g, void* l) {
    __builtin_amdgcn_global_load_lds(
        (const __attribute__((address_space(1))) void*)g,
        (__attribute__((address_space(3))) void*)l, 16, 0, 0);
}

// ---------------------------------------------------------------------------
// k_prep_e (tiny): [0,4) e2 | [4,20) e fp16 swizzle + rowCnt zero + flags.
// (validated r17-r20 verbatim)
// ---------------------------------------------------------------------------
__global__ __launch_bounds__(256) void k_prep_e(const float* __restrict__ e,
                                                float* __restrict__ e2,
                                                unsigned short* __restrict__ eh,
                                                int* __restrict__ rowCnt,
                                                float* __restrict__ lossAcc,
                                                int* __restrict__ doneCnt) {
    const int bi = blockIdx.x;
    const int t  = threadIdx.x;
    if (bi < 4) {                      // ---- e2 ----
        int k = bi * 256 + t;
        const float4* p = (const float4*)(e + (size_t)k * 256);
        float s = 0.f;
#pragma unroll 4
        for (int c = 0; c < 64; ++c) {
            float4 v = p[c];
            s = fmaf(v.x, v.x, s); s = fmaf(v.y, v.y, s);
            s = fmaf(v.z, v.z, s); s = fmaf(v.w, v.w, s);
        }
        e2[k] = s;
    } else {                           // ---- eh swizzle + zero slices ----
        int bb = bi - 4;               // 0..15
        int k0 = bb * 64;
#pragma unroll 4
        for (int i = 0; i < 16; ++i) {
            int flat = i * 256 + t;
            int row = flat >> 6, ch = flat & 63;
            int slab = ch >> 4, s8p = (ch >> 1) & 7, half = ch & 1;
            int s8 = s8p ^ (row & 7);
            int d  = slab * 64 + s8 * 8 + half * 4;
            float4 v = *(const float4*)(e + (size_t)(k0 + row) * 256 + d);
            uint2 ph = { (unsigned)f2h(v.x) | ((unsigned)f2h(v.y) << 16),
                         (unsigned)f2h(v.z) | ((unsigned)f2h(v.w) << 16) };
            size_t off = (size_t)(k0 + row) * 256 + slab * 64 + s8p * 8 + half * 4;
            *(uint2*)(eh + off) = ph;
        }
        if (bb == 0 && t == 0) { lossAcc[0] = 0.f; doneCnt[0] = 0; }
#pragma unroll
        for (int j = 0; j < 8; ++j)
            rowCnt[bb * 2048 + j * 256 + t] = 0;
    }
}

// ---------------------------------------------------------------------------
// k_score v6 = r19-validated v4b main (plain __syncthreads; r20's counted
// vmcnt reverted on evidence) + FUSED SELECT TAIL. Each block covers all
// 1024 codes for its 64 rows, so at loop end its candidate lists are FINAL.
// Visibility: vmcnt(0) + __threadfence (L1 refresh; L2 = coherence point)
// + barrier. Tail = r19-validated k_select v5 logic (wave w owns rows
// 8w..8w+8; zstage in retired B-buffer LDS; z2 from z2L; e2 from e2L).
// ---------------------------------------------------------------------------
__global__ __launch_bounds__(512) void k_score(
        const float* __restrict__ z,
        const float* __restrict__ e,
        const unsigned short* __restrict__ eh,
        const float* __restrict__ e2,
        int* __restrict__ rowCnt, uint2* __restrict__ rowCand,
        float* __restrict__ outIdx, int* __restrict__ wsIdx) {
    __shared__ unsigned short lds[32768];  // A | B0 | B1 (64 KB)
    __shared__ float e2L[1024];            // 4 KB
    __shared__ float z2L[64];              // 256 B

    float* tile = (float*)&lds[16384];     // 64x64 f32 (16 KB) overlays B0

    const int t    = threadIdx.x;          // 0..511
    const int lane = t & 63;
    const int w    = t >> 6;               // 0..7
    const int wr   = w >> 1;               // row-group 0..3
    const int wc   = w & 1;                // code-half 0..1
    const int c    = lane & 15;
    const int kq   = lane >> 4;            // 0..3
    const int n0   = blockIdx.x * 64;
    const int b    = n0 >> 10;
    const int nl0  = n0 & 1023;

    e2L[t]       = e2[t];
    e2L[t + 512] = e2[t + 512];

    // ---- phase 0: z stage + fp16 A-panel build + z2 chain (validated) ----
    {
        float zs = 0.f;
        const int prow = t & 63;
        const int uu0  = (t >> 6) * 4;
        for (int ch = 0; ch < 4; ++ch) {
            const int d0 = ch * 64;
            __syncthreads();
#pragma unroll
            for (int i = 0; i < 2; ++i) {
                int flat = i * 512 + t;
                int dd = flat >> 4, q = flat & 15;
                float4 v = *(const float4*)(z + (size_t)b * 262144 +
                                            (size_t)(d0 + dd) * 1024 + nl0 + q * 4);
                int j0 = q * 4, sx = dd & 31;
                tile[dd * 64 + ((j0 + 0) ^ sx)] = v.x;
                tile[dd * 64 + ((j0 + 1) ^ sx)] = v.y;
                tile[dd * 64 + ((j0 + 2) ^ sx)] = v.z;
                tile[dd * 64 + ((j0 + 3) ^ sx)] = v.w;
            }
            __syncthreads();
            if (t < 64) {
#pragma unroll 16
                for (int dd = 0; dd < 64; ++dd) {
                    float v = tile[dd * 64 + (t ^ (dd & 31))];
                    zs = fmaf(v, v, zs);
                }
            }
#pragma unroll
            for (int u = uu0; u < uu0 + 4; ++u) {
                int dlo = u * 2;
                float a0 = tile[dlo * 64 + (prow ^ (dlo & 31))];
                float a1 = tile[(dlo + 1) * 64 + (prow ^ ((dlo + 1) & 31))];
                unsigned int pk = (unsigned)f2h(a0) | ((unsigned)f2h(a1) << 16);
                int g = u >> 2, w32 = u & 3;
                *(unsigned int*)&lds[prow * 256 + d0 +
                                     ((g ^ (prow & 7)) * 8) + w32 * 2] = pk;
            }
        }
        __syncthreads();
        if (t < 64) z2L[t] = zs;
    }

#define STAGE_B(S, BUF)                                                      \
    do {                                                                     \
        int kc_ = (S) >> 2, dg_ = (S) & 3;                                   \
        _Pragma("unroll")                                                    \
        for (int p = 0; p < 2; ++p) {                                        \
            int slot = p * 512 + t;                                          \
            int code = slot >> 3, sg = slot & 7;                             \
            gload16(eh + (size_t)(kc_ * 128 + code) * 256 + dg_ * 64 + sg * 8, \
                    &lds[16384 + (BUF) * 8192 + (p * 512 + w * 64) * 8]);    \
        }                                                                    \
    } while (0)

    f32x4 acc[4];
#pragma unroll
    for (int cf = 0; cf < 4; ++cf) acc[cf] = (f32x4){0.f, 0.f, 0.f, 0.f};
    float m_run[4] = { 3.4e38f, 3.4e38f, 3.4e38f, 3.4e38f };

    const int rl = wr * 16 + c;
    STAGE_B(0, 0);
    __syncthreads();

    for (int s = 0; s < 32; ++s) {
        if (s < 31) STAGE_B(s + 1, (s + 1) & 1);
        {
            const int dg = s & 3;
            const unsigned short* Bb = &lds[16384 + (s & 1) * 8192];
#pragma unroll
            for (int ks = 0; ks < 2; ++ks) {
                int wo = ks * 4 + kq;
                half8 a = *(const half8*)&lds[rl * 256 + dg * 64 +
                                              (wo ^ (rl & 7)) * 8];
                half8 bfr[4];
#pragma unroll
                for (int cf = 0; cf < 4; ++cf) {
                    int cl = wc * 64 + cf * 16 + c;
                    bfr[cf] = *(const half8*)&Bb[cl * 64 + (wo ^ (cl & 7)) * 8];
                }
#pragma unroll
                for (int cf = 0; cf < 4; ++cf)
                    acc[cf] = __builtin_amdgcn_mfma_f32_16x16x32_f16(
                        a, bfr[cf], acc[cf], 0, 0, 0);
            }
        }
        if ((s & 3) == 3) {
            const int kc = s >> 2;
            float e2r[4];
#pragma unroll
            for (int cf = 0; cf < 4; ++cf)
                e2r[cf] = e2L[kc * 128 + wc * 64 + cf * 16 + c];
            float mnew[4];
#pragma unroll
            for (int reg = 0; reg < 4; ++reg) {
                float mm = 3.4e38f;
#pragma unroll
                for (int cf = 0; cf < 4; ++cf)
                    mm = fminf(mm, fmaf(-2.f, acc[cf][reg], e2r[cf]));
                mnew[reg] = mm;
            }
#pragma unroll
            for (int m = 1; m < 16; m <<= 1)
#pragma unroll
                for (int reg = 0; reg < 4; ++reg)
                    mnew[reg] = fminf(mnew[reg], __shfl_xor(mnew[reg], m, 64));
#pragma unroll
            for (int reg = 0; reg < 4; ++reg)
                mnew[reg] = fminf(mnew[reg], m_run[reg]);
#pragma unroll
            for (int cf = 0; cf < 4; ++cf)
#pragma unroll
                for (int reg = 0; reg < 4; ++reg) {
                    float sv = fmaf(-2.f, acc[cf][reg], e2r[cf]);
                    if (sv <= mnew[reg] + MARGIN) {
                        int n = n0 + wr * 16 + kq * 4 + reg;
                        int k = kc * 128 + wc * 64 + cf * 16 + c;
                        int pos = atomicAdd(&rowCnt[n], 1);
                        if (pos < RCAP) {
                            uint2 cd; cd.x = (unsigned)k;
                            cd.y = __float_as_uint(sv);
                            rowCand[n * RCAP + pos] = cd;
                        }
                    }
                }
#pragma unroll
            for (int reg = 0; reg < 4; ++reg) m_run[reg] = mnew[reg];
#pragma unroll
            for (int cf = 0; cf < 4; ++cf) acc[cf] = (f32x4){0.f, 0.f, 0.f, 0.f};
        }
        __syncthreads();
    }
#undef STAGE_B

    // ---- fused select tail ----
    asm volatile("s_waitcnt vmcnt(0)" ::: "memory");
    __threadfence();
    __syncthreads();
    {
        float* zst = (float*)&lds[16384 + w * 512];   // 256 f32 per wave
        for (int rr = 0; rr < 8; ++rr) {
            const int n = n0 + w * 8 + rr;
            const int rloc = w * 8 + rr;
            const int cnt = rowCnt[n];
            const float* zrow = z + (size_t)b * 262144 + (n & 1023);
            unsigned long long key = 0xFFFFFFFFFFFFFFFFULL;
            if (cnt <= RCAP) {
                float sc = 3.4e38f;
                int   k = 0;
                if (lane < cnt) {
                    uint2 cd = rowCand[n * RCAP + lane];
                    k = (int)cd.x;
                    sc = __uint_as_float(cd.y);
                }
                float gmin = sc;
#pragma unroll
                for (int m = 1; m < 64; m <<= 1)
                    gmin = fminf(gmin, __shfl_xor(gmin, m, 64));
                bool surv = (lane < cnt) && (sc <= gmin + MARGIN);
                unsigned long long bal = __ballot(surv);
                if (__popcll(bal) == 1) {
                    if (surv) { outIdx[n] = (float)k; wsIdx[n] = k; }
                    continue;
                }
#pragma unroll
                for (int j = 0; j < 4; ++j)
                    zst[lane + 64 * j] = zrow[(size_t)(lane + 64 * j) * 1024];
                if (surv) {
                    const float* erk = e + (size_t)k * 256;
                    float ze = 0.f;
#pragma unroll 8
                    for (int d = 0; d < 256; ++d)
                        ze = fmaf(zst[d], erk[d], ze);
                    float t1 = z2L[rloc] + e2L[k];
                    float dist = fmaf(-2.f, ze, t1);
                    key = ((unsigned long long)__float_as_uint(dist) << 32) |
                          (unsigned int)k;
                }
            } else {
#pragma unroll
                for (int j = 0; j < 4; ++j)
                    zst[lane + 64 * j] = zrow[(size_t)(lane + 64 * j) * 1024];
                const float z2r = z2L[rloc];
                for (int j = 0; j < 16; ++j) {
                    int k = lane * 16 + j;
                    const float* erk = e + (size_t)k * 256;
                    float ze = 0.f;
#pragma unroll 8
                    for (int d = 0; d < 256; ++d)
                        ze = fmaf(zst[d], erk[d], ze);
                    float t1 = z2r + e2L[k];
                    float dist = fmaf(-2.f, ze, t1);
                    unsigned long long kk =
                        ((unsigned long long)__float_as_uint(dist) << 32) |
                        (unsigned int)k;
                    if (kk < key) key = kk;
                }
            }
#pragma unroll
            for (int m = 1; m < 64; m <<= 1) {
                unsigned long long o = __shfl_xor(key, m, 64);
                if (o < key) key = o;
            }
            if (lane == 0) {
                int k = (int)(unsigned int)(key & 0xFFFFFFFFULL);
                outIdx[n] = (float)k;
                wsIdx[n]  = k;
            }
        }
    }
}

// ---------------------------------------------------------------------------
// k_epilogue v7: zero-LDS, zero-barrier gather. Block = (b, 16 d's, all
// 1024 nl), grid 512. z/out = perfect 4KB-row streams; per thread the 4
// selected e-rows' [d0,d0+16) slices are 64B-contiguous (4 float4 gathers
// per row, one L1 line) -> L1/L2-resident with ~33 independent loads of
// ILP. NUMERICS per element identical (validated). Ticket finalize.
// ---------------------------------------------------------------------------
__global__ __launch_bounds__(256) void k_epilogue(const float* __restrict__ z,
                                                  const float* __restrict__ e,
                                                  const int* __restrict__ wsIdx,
                                                  float* __restrict__ outZ,
                                                  float* __restrict__ lossAcc,
                                                  int* __restrict__ doneCnt,
                                                  float* __restrict__ outLoss) {
    __shared__ float wsum[4];
    const int t  = threadIdx.x;
    const int b  = blockIdx.x >> 4;
    const int d0 = (blockIdx.x & 15) * 16;
    const int nl = t * 4;
    const size_t zb = (size_t)b * 262144;

    int4 idx4 = *(const int4*)&wsIdx[b * 1024 + nl];
    float ev[4][16];
    const int rows[4] = { idx4.x, idx4.y, idx4.z, idx4.w };
#pragma unroll
    for (int j = 0; j < 4; ++j) {
        const float* er = e + (size_t)rows[j] * 256 + d0;
#pragma unroll
        for (int q = 0; q < 4; ++q) {
            float4 v = *(const float4*)(er + q * 4);
            ev[j][q * 4 + 0] = v.x; ev[j][q * 4 + 1] = v.y;
            ev[j][q * 4 + 2] = v.z; ev[j][q * 4 + 3] = v.w;
        }
    }

    float s = 0.f;
#pragma unroll
    for (int dd = 0; dd < 16; ++dd) {
        size_t go = zb + (size_t)(d0 + dd) * 1024 + nl;
        float4 z4 = *(const float4*)(z + go);
        float4 o; float df;
        df = ev[0][dd] - z4.x; s = fmaf(df, df, s); o.x = z4.x + df;
        df = ev[1][dd] - z4.y; s = fmaf(df, df, s); o.y = z4.y + df;
        df = ev[2][dd] - z4.z; s = fmaf(df, df, s); o.z = z4.z + df;
        df = ev[3][dd] - z4.w; s = fmaf(df, df, s); o.w = z4.w + df;
        *(float4*)(outZ + go) = o;
    }

#pragma unroll
    for (int off = 32; off > 0; off >>= 1) s += __shfl_down(s, off, 64);
    if ((t & 63) == 0) wsum[t >> 6] = s;
    __syncthreads();
    if (t == 0) {
        float bs = ((wsum[0] + wsum[1]) + wsum[2]) + wsum[3];
        atomicAdd(lossAcc, bs);
        __threadfence();
        int tk = atomicAdd(doneCnt, 1);
        if (tk == 511) {
            float L = atomicAdd(lossAcc, 0.0f);
            float m = L * (1.0f / 8388608.0f);
            outLoss[0] = m + 0.25f * m;
        }
    }
}

// ---------------------------------------------------------------------------
extern "C" void kernel_launch(void* const* d_in, const int* in_sizes, int n_in,
                              void* d_out, int out_size, void* d_ws, size_t ws_size,
                              hipStream_t stream) {
    const float* z = (const float*)d_in[0];   // (32,256,32,32)
    const float* e = (const float*)d_in[1];   // (1024,256)
    float* out     = (float*)d_out;
    float* outIdx  = out + 8388608;
    float* outLoss = out + 8421376;

    float* e2      = (float*)d_ws;                        // 1024 f
    float* lossAcc = e2 + 1024;                           // own line
    int*   doneCnt = (int*)(lossAcc + 64);                // own line
    int*   rowCnt  = doneCnt + 64;                        // 32768 i
    int*   wsIdx   = rowCnt + 32768;                      // 32768 i
    uintptr_t p = (uintptr_t)(wsIdx + 32768);
    p = (p + 255) & ~(uintptr_t)255;
    uint2* rowCand = (uint2*)p;                           // 32768*48 uint2
    unsigned short* eh = (unsigned short*)(rowCand + 32768 * RCAP);

    k_prep_e<<<20, 256, 0, stream>>>(e, e2, eh, rowCnt, lossAcc, doneCnt);
    k_score<<<512, 512, 0, stream>>>(z, e, eh, e2, rowCnt, rowCand,
                                     outIdx, wsIdx);
    k_epilogue<<<512, 256, 0, stream>>>(z, e, wsIdx, out, lossAcc,
                                        doneCnt, outLoss);
}

// Round 22
// 142.767 us; speedup vs baseline: 1.5536x; 1.5536x over previous
//
#include <hip/hip_runtime.h>
#include <hip/hip_fp16.h>

#define MARGIN 6e-4f
#define RCAP 48

typedef __attribute__((ext_vector_type(8))) _Float16 half8;
typedef __attribute__((ext_vector_type(4))) float f32x4;

// RNE f32 -> fp16 bits (validated r12-r21)
__device__ __forceinline__ unsigned short f2h(float x) {
    __half h = __float2half(x);
    return *reinterpret_cast<unsigned short*>(&h);
}
__device__ __forceinline__ void gload16(const void* g, void* l) {
    __builtin_amdgcn_global_load_lds(
        (const __attribute__((address_space(1))) void*)g,
        (__attribute__((address_space(3))) void*)l, 16, 0, 0);
}

// ---------------------------------------------------------------------------
// k_prep_e (tiny): [0,4) e2 | [4,20) e fp16 swizzle + rowCnt zero + flags.
// (validated r17-r21 verbatim)
// ---------------------------------------------------------------------------
__global__ __launch_bounds__(256) void k_prep_e(const float* __restrict__ e,
                                                float* __restrict__ e2,
                                                unsigned short* __restrict__ eh,
                                                int* __restrict__ rowCnt,
                                                float* __restrict__ lossAcc,
                                                int* __restrict__ doneCnt) {
    const int bi = blockIdx.x;
    const int t  = threadIdx.x;
    if (bi < 4) {                      // ---- e2 ----
        int k = bi * 256 + t;
        const float4* p = (const float4*)(e + (size_t)k * 256);
        float s = 0.f;
#pragma unroll 4
        for (int c = 0; c < 64; ++c) {
            float4 v = p[c];
            s = fmaf(v.x, v.x, s); s = fmaf(v.y, v.y, s);
            s = fmaf(v.z, v.z, s); s = fmaf(v.w, v.w, s);
        }
        e2[k] = s;
    } else {                           // ---- eh swizzle + zero slices ----
        int bb = bi - 4;               // 0..15
        int k0 = bb * 64;
#pragma unroll 4
        for (int i = 0; i < 16; ++i) {
            int flat = i * 256 + t;
            int row = flat >> 6, ch = flat & 63;
            int slab = ch >> 4, s8p = (ch >> 1) & 7, half = ch & 1;
            int s8 = s8p ^ (row & 7);
            int d  = slab * 64 + s8 * 8 + half * 4;
            float4 v = *(const float4*)(e + (size_t)(k0 + row) * 256 + d);
            uint2 ph = { (unsigned)f2h(v.x) | ((unsigned)f2h(v.y) << 16),
                         (unsigned)f2h(v.z) | ((unsigned)f2h(v.w) << 16) };
            size_t off = (size_t)(k0 + row) * 256 + slab * 64 + s8p * 8 + half * 4;
            *(uint2*)(eh + off) = ph;
        }
        if (bb == 0 && t == 0) { lossAcc[0] = 0.f; doneCnt[0] = 0; }
#pragma unroll
        for (int j = 0; j < 8; ++j)
            rowCnt[bb * 2048 + j * 256 + t] = 0;
    }
}

// ---------------------------------------------------------------------------
// k_score v6b = r21 minus __threadfence in the tail. r21 evidence: main loop
// unchanged (MfmaUtil diluted exactly by dur ratio) but tail cost ~120us and
// FETCH rose 18.5->34.8 MB: the agent-scope fence forces L2 writeback/inv on
// the non-coherent per-XCD L2s -> every tail re-pulled warm data from HBM.
// The fence is UNNECESSARY: a workgroup runs on one CU; this block is the
// sole writer of its rows' rowCnt/rowCand; rowCand stores are write-through;
// rowCnt is only atomicAdd'd (L2, L1-bypassing) and first-LOADED in the tail
// (guaranteed L1 miss -> L2's final value). Per-wave vmcnt(0) + barrier
// (= __syncthreads semantics) is sufficient.
// ---------------------------------------------------------------------------
__global__ __launch_bounds__(512) void k_score(
        const float* __restrict__ z,
        const float* __restrict__ e,
        const unsigned short* __restrict__ eh,
        const float* __restrict__ e2,
        int* __restrict__ rowCnt, uint2* __restrict__ rowCand,
        float* __restrict__ outIdx, int* __restrict__ wsIdx) {
    __shared__ unsigned short lds[32768];  // A | B0 | B1 (64 KB)
    __shared__ float e2L[1024];            // 4 KB
    __shared__ float z2L[64];              // 256 B

    float* tile = (float*)&lds[16384];     // 64x64 f32 (16 KB) overlays B0

    const int t    = threadIdx.x;          // 0..511
    const int lane = t & 63;
    const int w    = t >> 6;               // 0..7
    const int wr   = w >> 1;               // row-group 0..3
    const int wc   = w & 1;                // code-half 0..1
    const int c    = lane & 15;
    const int kq   = lane >> 4;            // 0..3
    const int n0   = blockIdx.x * 64;
    const int b    = n0 >> 10;
    const int nl0  = n0 & 1023;

    e2L[t]       = e2[t];
    e2L[t + 512] = e2[t + 512];

    // ---- phase 0: z stage + fp16 A-panel build + z2 chain (validated) ----
    {
        float zs = 0.f;
        const int prow = t & 63;
        const int uu0  = (t >> 6) * 4;
        for (int ch = 0; ch < 4; ++ch) {
            const int d0 = ch * 64;
            __syncthreads();
#pragma unroll
            for (int i = 0; i < 2; ++i) {
                int flat = i * 512 + t;
                int dd = flat >> 4, q = flat & 15;
                float4 v = *(const float4*)(z + (size_t)b * 262144 +
                                            (size_t)(d0 + dd) * 1024 + nl0 + q * 4);
                int j0 = q * 4, sx = dd & 31;
                tile[dd * 64 + ((j0 + 0) ^ sx)] = v.x;
                tile[dd * 64 + ((j0 + 1) ^ sx)] = v.y;
                tile[dd * 64 + ((j0 + 2) ^ sx)] = v.z;
                tile[dd * 64 + ((j0 + 3) ^ sx)] = v.w;
            }
            __syncthreads();
            if (t < 64) {
#pragma unroll 16
                for (int dd = 0; dd < 64; ++dd) {
                    float v = tile[dd * 64 + (t ^ (dd & 31))];
                    zs = fmaf(v, v, zs);
                }
            }
#pragma unroll
            for (int u = uu0; u < uu0 + 4; ++u) {
                int dlo = u * 2;
                float a0 = tile[dlo * 64 + (prow ^ (dlo & 31))];
                float a1 = tile[(dlo + 1) * 64 + (prow ^ ((dlo + 1) & 31))];
                unsigned int pk = (unsigned)f2h(a0) | ((unsigned)f2h(a1) << 16);
                int g = u >> 2, w32 = u & 3;
                *(unsigned int*)&lds[prow * 256 + d0 +
                                     ((g ^ (prow & 7)) * 8) + w32 * 2] = pk;
            }
        }
        __syncthreads();
        if (t < 64) z2L[t] = zs;
    }

#define STAGE_B(S, BUF)                                                      \
    do {                                                                     \
        int kc_ = (S) >> 2, dg_ = (S) & 3;                                   \
        _Pragma("unroll")                                                    \
        for (int p = 0; p < 2; ++p) {                                        \
            int slot = p * 512 + t;                                          \
            int code = slot >> 3, sg = slot & 7;                             \
            gload16(eh + (size_t)(kc_ * 128 + code) * 256 + dg_ * 64 + sg * 8, \
                    &lds[16384 + (BUF) * 8192 + (p * 512 + w * 64) * 8]);    \
        }                                                                    \
    } while (0)

    f32x4 acc[4];
#pragma unroll
    for (int cf = 0; cf < 4; ++cf) acc[cf] = (f32x4){0.f, 0.f, 0.f, 0.f};
    float m_run[4] = { 3.4e38f, 3.4e38f, 3.4e38f, 3.4e38f };

    const int rl = wr * 16 + c;
    STAGE_B(0, 0);
    __syncthreads();

    for (int s = 0; s < 32; ++s) {
        if (s < 31) STAGE_B(s + 1, (s + 1) & 1);
        {
            const int dg = s & 3;
            const unsigned short* Bb = &lds[16384 + (s & 1) * 8192];
#pragma unroll
            for (int ks = 0; ks < 2; ++ks) {
                int wo = ks * 4 + kq;
                half8 a = *(const half8*)&lds[rl * 256 + dg * 64 +
                                              (wo ^ (rl & 7)) * 8];
                half8 bfr[4];
#pragma unroll
                for (int cf = 0; cf < 4; ++cf) {
                    int cl = wc * 64 + cf * 16 + c;
                    bfr[cf] = *(const half8*)&Bb[cl * 64 + (wo ^ (cl & 7)) * 8];
                }
#pragma unroll
                for (int cf = 0; cf < 4; ++cf)
                    acc[cf] = __builtin_amdgcn_mfma_f32_16x16x32_f16(
                        a, bfr[cf], acc[cf], 0, 0, 0);
            }
        }
        if ((s & 3) == 3) {
            const int kc = s >> 2;
            float e2r[4];
#pragma unroll
            for (int cf = 0; cf < 4; ++cf)
                e2r[cf] = e2L[kc * 128 + wc * 64 + cf * 16 + c];
            float mnew[4];
#pragma unroll
            for (int reg = 0; reg < 4; ++reg) {
                float mm = 3.4e38f;
#pragma unroll
                for (int cf = 0; cf < 4; ++cf)
                    mm = fminf(mm, fmaf(-2.f, acc[cf][reg], e2r[cf]));
                mnew[reg] = mm;
            }
#pragma unroll
            for (int m = 1; m < 16; m <<= 1)
#pragma unroll
                for (int reg = 0; reg < 4; ++reg)
                    mnew[reg] = fminf(mnew[reg], __shfl_xor(mnew[reg], m, 64));
#pragma unroll
            for (int reg = 0; reg < 4; ++reg)
                mnew[reg] = fminf(mnew[reg], m_run[reg]);
#pragma unroll
            for (int cf = 0; cf < 4; ++cf)
#pragma unroll
                for (int reg = 0; reg < 4; ++reg) {
                    float sv = fmaf(-2.f, acc[cf][reg], e2r[cf]);
                    if (sv <= mnew[reg] + MARGIN) {
                        int n = n0 + wr * 16 + kq * 4 + reg;
                        int k = kc * 128 + wc * 64 + cf * 16 + c;
                        int pos = atomicAdd(&rowCnt[n], 1);
                        if (pos < RCAP) {
                            uint2 cd; cd.x = (unsigned)k;
                            cd.y = __float_as_uint(sv);
                            rowCand[n * RCAP + pos] = cd;
                        }
                    }
                }
#pragma unroll
            for (int reg = 0; reg < 4; ++reg) m_run[reg] = mnew[reg];
#pragma unroll
            for (int cf = 0; cf < 4; ++cf) acc[cf] = (f32x4){0.f, 0.f, 0.f, 0.f};
        }
        __syncthreads();
    }
#undef STAGE_B

    // ---- fused select tail (NO threadfence — see header comment) ----
    asm volatile("s_waitcnt vmcnt(0)" ::: "memory");
    __syncthreads();
    {
        float* zst = (float*)&lds[16384 + w * 512];   // 256 f32 per wave
        for (int rr = 0; rr < 8; ++rr) {
            const int n = n0 + w * 8 + rr;
            const int rloc = w * 8 + rr;
            const int cnt = rowCnt[n];
            const float* zrow = z + (size_t)b * 262144 + (n & 1023);
            unsigned long long key = 0xFFFFFFFFFFFFFFFFULL;
            if (cnt <= RCAP) {
                float sc = 3.4e38f;
                int   k = 0;
                if (lane < cnt) {
                    uint2 cd = rowCand[n * RCAP + lane];
                    k = (int)cd.x;
                    sc = __uint_as_float(cd.y);
                }
                float gmin = sc;
#pragma unroll
                for (int m = 1; m < 64; m <<= 1)
                    gmin = fminf(gmin, __shfl_xor(gmin, m, 64));
                bool surv = (lane < cnt) && (sc <= gmin + MARGIN);
                unsigned long long bal = __ballot(surv);
                if (__popcll(bal) == 1) {          // sole survivor == argmin
                    if (surv) { outIdx[n] = (float)k; wsIdx[n] = k; }
                    continue;                       // bal wave-uniform
                }
#pragma unroll
                for (int j = 0; j < 4; ++j)
                    zst[lane + 64 * j] = zrow[(size_t)(lane + 64 * j) * 1024];
                if (surv) {
                    const float* erk = e + (size_t)k * 256;
                    float ze = 0.f;
#pragma unroll 8
                    for (int d = 0; d < 256; ++d)
                        ze = fmaf(zst[d], erk[d], ze);
                    float t1 = z2L[rloc] + e2L[k];
                    float dist = fmaf(-2.f, ze, t1);
                    key = ((unsigned long long)__float_as_uint(dist) << 32) |
                          (unsigned int)k;
                }
            } else {                    // deterministic fallback: full scan
#pragma unroll
                for (int j = 0; j < 4; ++j)
                    zst[lane + 64 * j] = zrow[(size_t)(lane + 64 * j) * 1024];
                const float z2r = z2L[rloc];
                for (int j = 0; j < 16; ++j) {
                    int k = lane * 16 + j;
                    const float* erk = e + (size_t)k * 256;
                    float ze = 0.f;
#pragma unroll 8
                    for (int d = 0; d < 256; ++d)
                        ze = fmaf(zst[d], erk[d], ze);
                    float t1 = z2r + e2L[k];
                    float dist = fmaf(-2.f, ze, t1);
                    unsigned long long kk =
                        ((unsigned long long)__float_as_uint(dist) << 32) |
                        (unsigned int)k;
                    if (kk < key) key = kk;
                }
            }
#pragma unroll
            for (int m = 1; m < 64; m <<= 1) {
                unsigned long long o = __shfl_xor(key, m, 64);
                if (o < key) key = o;
            }
            if (lane == 0) {
                int k = (int)(unsigned int)(key & 0xFFFFFFFFULL);
                outIdx[n] = (float)k;
                wsIdx[n]  = k;
            }
        }
    }
}

// ---------------------------------------------------------------------------
// k_epilogue v7 (validated r21, ~30us by subtraction): zero-LDS gather.
// Block = (b, 16 d's, all 1024 nl), grid 512. z/out = perfect 4KB-row
// streams; per thread the 4 selected e-rows' [d0,d0+16) slices are 64B-
// contiguous (L1-line gathers). NUMERICS per element identical. Ticket
// finalize.
// ---------------------------------------------------------------------------
__global__ __launch_bounds__(256) void k_epilogue(const float* __restrict__ z,
                                                  const float* __restrict__ e,
                                                  const int* __restrict__ wsIdx,
                                                  float* __restrict__ outZ,
                                                  float* __restrict__ lossAcc,
                                                  int* __restrict__ doneCnt,
                                                  float* __restrict__ outLoss) {
    __shared__ float wsum[4];
    const int t  = threadIdx.x;
    const int b  = blockIdx.x >> 4;
    const int d0 = (blockIdx.x & 15) * 16;
    const int nl = t * 4;
    const size_t zb = (size_t)b * 262144;

    int4 idx4 = *(const int4*)&wsIdx[b * 1024 + nl];
    float ev[4][16];
    const int rows[4] = { idx4.x, idx4.y, idx4.z, idx4.w };
#pragma unroll
    for (int j = 0; j < 4; ++j) {
        const float* er = e + (size_t)rows[j] * 256 + d0;
#pragma unroll
        for (int q = 0; q < 4; ++q) {
            float4 v = *(const float4*)(er + q * 4);
            ev[j][q * 4 + 0] = v.x; ev[j][q * 4 + 1] = v.y;
            ev[j][q * 4 + 2] = v.z; ev[j][q * 4 + 3] = v.w;
        }
    }

    float s = 0.f;
#pragma unroll
    for (int dd = 0; dd < 16; ++dd) {
        size_t go = zb + (size_t)(d0 + dd) * 1024 + nl;
        float4 z4 = *(const float4*)(z + go);
        float4 o; float df;
        df = ev[0][dd] - z4.x; s = fmaf(df, df, s); o.x = z4.x + df;
        df = ev[1][dd] - z4.y; s = fmaf(df, df, s); o.y = z4.y + df;
        df = ev[2][dd] - z4.z; s = fmaf(df, df, s); o.z = z4.z + df;
        df = ev[3][dd] - z4.w; s = fmaf(df, df, s); o.w = z4.w + df;
        *(float4*)(outZ + go) = o;
    }

#pragma unroll
    for (int off = 32; off > 0; off >>= 1) s += __shfl_down(s, off, 64);
    if ((t & 63) == 0) wsum[t >> 6] = s;
    __syncthreads();
    if (t == 0) {
        float bs = ((wsum[0] + wsum[1]) + wsum[2]) + wsum[3];
        atomicAdd(lossAcc, bs);
        __threadfence();
        int tk = atomicAdd(doneCnt, 1);
        if (tk == 511) {
            float L = atomicAdd(lossAcc, 0.0f);
            float m = L * (1.0f / 8388608.0f);
            outLoss[0] = m + 0.25f * m;
        }
    }
}

// ---------------------------------------------------------------------------
extern "C" void kernel_launch(void* const* d_in, const int* in_sizes, int n_in,
                              void* d_out, int out_size, void* d_ws, size_t ws_size,
                              hipStream_t stream) {
    const float* z = (const float*)d_in[0];   // (32,256,32,32)
    const float* e = (const float*)d_in[1];   // (1024,256)
    float* out     = (float*)d_out;
    float* outIdx  = out + 8388608;
    float* outLoss = out + 8421376;

    float* e2      = (float*)d_ws;                        // 1024 f
    float* lossAcc = e2 + 1024;                           // own line
    int*   doneCnt = (int*)(lossAcc + 64);                // own line
    int*   rowCnt  = doneCnt + 64;                        // 32768 i
    int*   wsIdx   = rowCnt + 32768;                      // 32768 i
    uintptr_t p = (uintptr_t)(wsIdx + 32768);
    p = (p + 255) & ~(uintptr_t)255;
    uint2* rowCand = (uint2*)p;                           // 32768*48 uint2
    unsigned short* eh = (unsigned short*)(rowCand + 32768 * RCAP);

    k_prep_e<<<20, 256, 0, stream>>>(e, e2, eh, rowCnt, lossAcc, doneCnt);
    k_score<<<512, 512, 0, stream>>>(z, e, eh, e2, rowCnt, rowCand,
                                     outIdx, wsIdx);
    k_epilogue<<<512, 256, 0, stream>>>(z, e, wsIdx, out, lossAcc,
                                        doneCnt, outLoss);
}